// Round 20
// baseline (461.256 us; speedup 1.0000x reference)
//
#include <hip/hip_runtime.h>

#define BATCH 256
#define DIM 512
#define NACT 3
#define NMEM 25000
#define KNB 50
#define H1N 256
#define H2N 128
#define NSTEPS 5
#define KDELTA 0.001f

#define TB 128
#define TN 64
#define BK 32
#define NCH (DIM / BK)               // 16 k-chunks
#define LDP 40                       // padded LDS row stride (shorts): 80 B = 20 banks -> conflict-free, 16B-aligned
#define NYT ((NMEM + TN - 1) / TN)   // 391 n-tiles

#define CAP 2048           // candidate buffer cap
#define MAXPT 12           // per-(row,tile) candidate slots; P(Poisson(0.52)>12) ~ 1e-15
#define ZTHR 2.40f         // expected ~205 candidates; P(cnt<128) ~ 3e-8 for Gaussian keys

typedef __attribute__((ext_vector_type(8))) short short8;
typedef __attribute__((ext_vector_type(4))) float f32x4;

__device__ __forceinline__ unsigned short bf16rn(float f) {
    unsigned u = __float_as_uint(f);
    u += 0x7FFFu + ((u >> 16) & 1u);
    return (unsigned short)(u >> 16);
}
__device__ __forceinline__ float blo(unsigned u) { return __uint_as_float(u << 16); }
__device__ __forceinline__ float bhi(unsigned u) { return __uint_as_float(u & 0xFFFF0000u); }

// ---------- prep keys: f32 -> bf16 copy + row norms (one wave per row) ----------
__global__ __launch_bounds__(256)
void prep_keys_kernel(const float* __restrict__ rows, unsigned short* __restrict__ kb,
                      float* __restrict__ kn, int nrows) {
    int wave = threadIdx.x >> 6, lane = threadIdx.x & 63;
    int r = blockIdx.x * 4 + wave;
    if (r >= nrows) return;
    const float* p = rows + (size_t)r * DIM;
    float4 v0 = *(const float4*)(p + lane * 8);
    float4 v1 = *(const float4*)(p + lane * 8 + 4);
    float f[8] = {v0.x, v0.y, v0.z, v0.w, v1.x, v1.y, v1.z, v1.w};
    short8 hv;
    float s = 0.f;
    #pragma unroll
    for (int i = 0; i < 8; ++i) { hv[i] = (short)bf16rn(f[i]); s += f[i] * f[i]; }
    *(short8*)(kb + (size_t)r * DIM + lane * 8) = hv;
    for (int off = 32; off; off >>= 1) s += __shfl_down(s, off);
    if (lane == 0) kn[r] = s;
}

// ---------- per-action kn stats (mean, var) ----------
__global__ __launch_bounds__(256)
void knstats_kernel(const float* __restrict__ kn, float* __restrict__ knm,
                    float* __restrict__ knv) {
    int a = blockIdx.x, tid = threadIdx.x;
    __shared__ float ss[256], qq[256];
    float s = 0.f, q = 0.f;
    for (int i = tid; i < NMEM; i += 256) {
        float v = kn[a * NMEM + i];
        s += v; q += v * v;
    }
    ss[tid] = s; qq[tid] = q;
    __syncthreads();
    for (int st = 128; st > 0; st >>= 1) {
        if (tid < st) { ss[tid] += ss[tid + st]; qq[tid] += qq[tid + st]; }
        __syncthreads();
    }
    if (tid == 0) {
        float mean = ss[0] / (float)NMEM;
        knm[a] = mean;
        knv[a] = fmaxf(qq[0] / (float)NMEM - mean * mean, 0.f);
    }
}

// ---------- group batch rows by action, all steps in one launch ----------
__global__ __launch_bounds__(256)
void group_all_kernel(const int* __restrict__ actions,
                      int* __restrict__ perm, int* __restrict__ cnt) {
    int step = blockIdx.x;
    __shared__ int lcnt[NACT];
    __shared__ int lperm[NACT * BATCH];
    int tid = threadIdx.x;
    if (tid < NACT) lcnt[tid] = 0;
    __syncthreads();
    int a = actions[tid * NSTEPS + step];
    int pos = atomicAdd(&lcnt[a], 1);
    lperm[a * BATCH + pos] = tid;
    __syncthreads();
    if (tid < NACT) cnt[step * 4 + tid] = lcnt[tid];
    for (int aa = 0; aa < NACT; ++aa) {
        int c = lcnt[aa];
        int f = (c > 0) ? lperm[aa * BATCH] : 0;
        for (int i = c + tid; i < BATCH; i += 256) lperm[aa * BATCH + i] = f;
    }
    __syncthreads();
    for (int i = tid; i < NACT * BATCH; i += 256)
        perm[step * NACT * BATCH + i] = lperm[i];
}

// ---------- step-0: prep x (bf16 + qn + analytic threshold) fused with first MLP ----------
// Tb is in the qn-LESS frame: d' = kn - 2 q.k  <  knm - z*s   (qn cancels)
__global__ __launch_bounds__(256)
void prep_predict_kernel(const float* __restrict__ x, unsigned short* __restrict__ eb,
                         float* __restrict__ qn, const int* __restrict__ actions,
                         const float* __restrict__ knm, const float* __restrict__ knv,
                         float* __restrict__ Tb, float* __restrict__ sw,
                         const float* __restrict__ w1, const float* __restrict__ b1,
                         const float* __restrict__ w2, const float* __restrict__ b2,
                         const float* __restrict__ w3, const float* __restrict__ b3,
                         float* __restrict__ out) {
    int b = blockIdx.x, tid = threadIdx.x;
    __shared__ float xs[DIM];
    __shared__ float red[256];
    __shared__ float h1[H1N];
    __shared__ float h2[H2N];
    float e0 = x[(size_t)b * DIM + tid];
    float e1 = x[(size_t)b * DIM + tid + 256];
    xs[tid] = e0; xs[tid + 256] = e1;
    eb[(size_t)b * DIM + tid] = bf16rn(e0);
    eb[(size_t)b * DIM + tid + 256] = bf16rn(e1);
    red[tid] = e0 * e0 + e1 * e1;
    __syncthreads();
    for (int s = 128; s > 0; s >>= 1) { if (tid < s) red[tid] += red[tid + s]; __syncthreads(); }
    if (tid == 0) {
        float q = red[0];
        qn[b] = q;
        int a0 = actions[b * NSTEPS];
        float s = sqrtf(knv[a0] + 4.f * q);
        Tb[b] = knm[a0] - ZTHR * s;     // qn-less frame
        sw[b] = s;
    }
    float acc = b1[tid];
    #pragma unroll 8
    for (int d = 0; d < DIM; ++d) acc = fmaf(xs[d], w1[d * H1N + tid], acc);
    h1[tid] = acc > 0.f ? acc : expm1f(acc);
    __syncthreads();
    if (tid < H2N) {
        float a2 = b2[tid];
        #pragma unroll 8
        for (int d = 0; d < H1N; ++d) a2 = fmaf(h1[d], w2[d * H2N + tid], a2);
        h2[tid] = a2 > 0.f ? a2 : expm1f(a2);
    }
    __syncthreads();
    if (tid < 5) {
        float p = b3[tid];
        for (int d = 0; d < H2N; ++d) p = fmaf(h2[d], w3[d * 5 + tid], p);
        float o = p;
        if (tid == 1) o = 1.0f / (1.0f + expf(-p));
        out[b * (6 * 5) + tid] = o;
    }
}

// ---------- approx distance GEMM + owner-computes LDS candidate collect ----------
// BK=32, padded LDS stride (no swizzle needed), 4 blocks/CU. Accumulation order identical to BK=64.
__global__ __launch_bounds__(256)
void dist_kernel(const unsigned short* __restrict__ eb, const unsigned short* __restrict__ kb,
                 const float* __restrict__ kn, const int* __restrict__ perm,
                 const int* __restrict__ cnt, const float* __restrict__ Tb,
                 unsigned* __restrict__ ccnt_t, unsigned short* __restrict__ candt) {
    int a = blockIdx.x;
    int c = cnt[a];
    int yt = blockIdx.y;
    int n0 = yt * TN;

    __shared__ __align__(16) unsigned short Qh[2][TB][LDP];
    __shared__ __align__(16) unsigned short Kh[2][TN][LDP];
    __shared__ int rows[TB];
    __shared__ float Tl[TB];
    __shared__ unsigned pcnt[TB];
    __shared__ unsigned short pids[TB][MAXPT];

    int tid = threadIdx.x;
    int lane = tid & 63, wave = tid >> 6;
    int wm = wave >> 1, wn = wave & 1;

    const int qr = tid >> 1, qc = (tid & 1) * 16;   // Q: 128 rows x 32k, 16 shorts/thread
    const int kr = tid >> 2, kc = (tid & 3) * 8;    // K: 64 rows x 32k, 8 shorts/thread
    int krow = (n0 + kr < NMEM) ? (n0 + kr) : (NMEM - 1);
    const unsigned short* ksrc = kb + ((size_t)a * NMEM + krow) * DIM + kc;

    int nn[2]; float knv2[2]; bool nvalid[2];
    #pragma unroll
    for (int nf = 0; nf < 2; ++nf) {
        nn[nf] = n0 + wn * 32 + nf * 16 + (lane & 15);
        nvalid[nf] = nn[nf] < NMEM;
        knv2[nf] = nvalid[nf] ? kn[a * NMEM + nn[nf]] : 0.f;
    }

    for (int tb0 = 0; tb0 < c; tb0 += TB) {
        __syncthreads();
        if (tid < TB) {
            int i = tb0 + tid;
            int rr = perm[a * BATCH + (i < c ? i : 0)];
            rows[tid] = rr;
            Tl[tid] = Tb[rr];
            pcnt[tid] = 0;
        }
        __syncthreads();

        const int mlim = c - tb0;   // rows >= mlim are duplicates of row 0
        const unsigned short* qsrc = eb + (size_t)rows[qr] * DIM + qc;
        f32x4 acc[4][2] = {};
        short8 qA[2], qB[2], kA, kB;

        // prologue: chunk0 -> A regs, chunk1 -> B regs; write A to buf0
        qA[0] = *(const short8*)(qsrc);
        qA[1] = *(const short8*)(qsrc + 8);
        kA = *(const short8*)(ksrc);
        qB[0] = *(const short8*)(qsrc + BK);
        qB[1] = *(const short8*)(qsrc + BK + 8);
        kB = *(const short8*)(ksrc + BK);
        *(short8*)&Qh[0][qr][qc] = qA[0];
        *(short8*)&Qh[0][qr][qc + 8] = qA[1];
        *(short8*)&Kh[0][kr][kc] = kA;
        __syncthreads();

        auto mfma_phase = [&](int B) {
            int kcol = (lane >> 4) * 8;
            short8 bv[2];
            #pragma unroll
            for (int nf = 0; nf < 2; ++nf) {
                int n = wn * 32 + nf * 16 + (lane & 15);
                bv[nf] = *(const short8*)&Kh[B][n][kcol];
            }
            #pragma unroll
            for (int mf = 0; mf < 4; ++mf) {
                if (wm * 64 + mf * 16 < mlim) {
                    int m = wm * 64 + mf * 16 + (lane & 15);
                    short8 av = *(const short8*)&Qh[B][m][kcol];
                    #pragma unroll
                    for (int nf = 0; nf < 2; ++nf)
                        acc[mf][nf] = __builtin_amdgcn_mfma_f32_16x16x32_bf16(av, bv[nf], acc[mf][nf], 0, 0, 0);
                }
            }
        };

        #pragma unroll
        for (int p = 0; p < NCH / 2; ++p) {
            const int it = 2 * p;
            if (it + 2 < NCH) {
                const int d0 = (it + 2) * BK;
                qA[0] = *(const short8*)(qsrc + d0);
                qA[1] = *(const short8*)(qsrc + d0 + 8);
                kA = *(const short8*)(ksrc + d0);
            }
            mfma_phase(0);
            {
                *(short8*)&Qh[1][qr][qc] = qB[0];
                *(short8*)&Qh[1][qr][qc + 8] = qB[1];
                *(short8*)&Kh[1][kr][kc] = kB;
                __syncthreads();
            }
            if (it + 3 < NCH) {
                const int d0 = (it + 3) * BK;
                qB[0] = *(const short8*)(qsrc + d0);
                qB[1] = *(const short8*)(qsrc + d0 + 8);
                kB = *(const short8*)(ksrc + d0);
            }
            mfma_phase(1);
            if (it + 2 < NCH) {
                *(short8*)&Qh[0][qr][qc] = qA[0];
                *(short8*)&Qh[0][qr][qc + 8] = qA[1];
                *(short8*)&Kh[0][kr][kc] = kA;
                __syncthreads();
            }
        }

        // ---- epilogue: threshold compare -> LDS collect (no dist-buffer store) ----
        #pragma unroll
        for (int mf = 0; mf < 4; ++mf) {
            if (wm * 64 + mf * 16 >= mlim) continue;
            #pragma unroll
            for (int r = 0; r < 4; ++r) {
                int m = wm * 64 + mf * 16 + (lane >> 4) * 4 + r;
                if (m >= mlim) continue;          // dup rows: never collect
                float Tv = Tl[m];
                #pragma unroll
                for (int nf = 0; nf < 2; ++nf) {
                    if (nvalid[nf]) {
                        float d = knv2[nf] - 2.0f * acc[mf][nf][r];
                        if (d < Tv) {
                            unsigned p = atomicAdd(&pcnt[m], 1u);
                            if (p < MAXPT) pids[m][p] = (unsigned short)nn[nf];
                        }
                    }
                }
            }
        }
        __syncthreads();
        // flush: plain stores, exclusive (b, yt) ownership
        if (tid < mlim) {
            int b = rows[tid];
            unsigned c0 = pcnt[tid];
            size_t slot = (size_t)b * NYT + yt;
            ccnt_t[slot] = c0;
            int w = c0 < MAXPT ? (int)c0 : MAXPT;
            for (int i = 0; i < w; ++i)
                candt[slot * MAXPT + i] = pids[tid][i];
        }
    }
}

// ---------- fused: assemble candidates -> exact refine -> top-50 -> gather -> MLP ----------
__global__ __launch_bounds__(1024)
void selgp_kernel(const float* __restrict__ emb, const unsigned short* __restrict__ eb,
                  const unsigned short* __restrict__ kb,
                  const float* __restrict__ keys, const float* __restrict__ kn,
                  const float* __restrict__ qn,
                  const unsigned* __restrict__ ccnt_t, const unsigned short* __restrict__ candt,
                  const float* __restrict__ Tb_in, const float* __restrict__ sw_in,
                  const int* __restrict__ actions, int step,
                  const float* __restrict__ vals,
                  const float* __restrict__ knm, const float* __restrict__ knv,
                  float* __restrict__ emb_out, unsigned short* __restrict__ eb_out,
                  float* __restrict__ qn_out, float* __restrict__ Tb_out,
                  float* __restrict__ sw_out,
                  const float* __restrict__ w1, const float* __restrict__ b1,
                  const float* __restrict__ w2, const float* __restrict__ b2,
                  const float* __restrict__ w3, const float* __restrict__ b3,
                  float* __restrict__ out) {
    __shared__ float qs[DIM];          // q row (refine), later reused as new-emb xs
    __shared__ int tcnt[512];
    __shared__ int ovfS;
    __shared__ unsigned cntS;
    __shared__ int candb[CAP];
    __shared__ float dex[CAP];
    __shared__ float wsel[KNB];
    __shared__ int   isel[KNB];
    __shared__ float wsumS;
    __shared__ float part[1024];
    __shared__ float red[512];
    __shared__ float h1[H1N];
    __shared__ float h2[H2N];

    int b = blockIdx.x, tid = threadIdx.x;
    int a = actions[b * NSTEPS + step];

    if (tid < 128) *(float4*)&qs[tid * 4] = *(const float4*)(emb + (size_t)b * DIM + tid * 4);

    // ---- assemble candidate list from per-tile slots ----
    int own = 0;
    if (tid < 512) tcnt[tid] = 0;
    if (tid == 0) ovfS = 0;
    __syncthreads();
    if (tid < NYT) {
        unsigned c0 = ccnt_t[(size_t)b * NYT + tid];
        own = (c0 > MAXPT) ? MAXPT : (int)c0;
        tcnt[tid] = own;
        if (c0 > MAXPT) ovfS = 1;     // benign race: any writer sets 1
    }
    __syncthreads();
    for (int off2 = 1; off2 < 512; off2 <<= 1) {
        int add = (tid < 512 && tid >= off2) ? tcnt[tid - off2] : 0;
        __syncthreads();
        if (tid < 512) tcnt[tid] += add;
        __syncthreads();
    }
    int C = tcnt[511];
    bool fb = (ovfS != 0) || (C < 128) || (C > CAP);
    if (!fb) {
        if (tid < NYT && own > 0) {
            int o = tcnt[tid] - own;
            size_t slot = (size_t)b * NYT + tid;
            for (int i = 0; i < own; ++i)
                candb[o + i] = (int)candt[slot * MAXPT + i];
        }
        __syncthreads();
    } else {
        // ---- fallback: brute-force recompute (bf16 inputs, f32 accum) + widen/tighten ----
        float T = Tb_in[b], sd = sw_in[b];
        for (int it = 0; it < 10; ++it) {
            if (tid == 0) cntS = 0;
            __syncthreads();
            for (int n = tid; n < NMEM; n += 1024) {
                const unsigned short* kr = kb + ((size_t)a * NMEM + n) * DIM;
                float dot = 0.f;
                for (int dd = 0; dd < DIM; dd += 2) {
                    unsigned u = *(const unsigned*)(kr + dd);
                    dot = fmaf(blo(u), qs[dd], dot);
                    dot = fmaf(bhi(u), qs[dd + 1], dot);
                }
                float d = kn[a * NMEM + n] - 2.0f * dot;
                if (d < T) { unsigned p = atomicAdd(&cntS, 1u); if (p < CAP) candb[p] = n; }
            }
            __syncthreads();
            if (cntS >= 128 && cntS <= CAP) break;
            T += (cntS > CAP) ? -0.3f * sd : 0.6f * sd;
            __syncthreads();
        }
        C = (int)cntS; if (C > CAP) C = CAP;
    }

    // ---- exact f32 refine (8 threads/cand, interleaved dims: conflict-free) ----
    float qnb = qn[b];
    const float* keysA = keys + (size_t)a * NMEM * DIM;
    {
        int cslot = tid >> 3, sub = tid & 7;
        int sweeps = (C + 127) >> 7;
        for (int sw = 0; sw < sweeps; ++sw) {
            int ci = sw * 128 + cslot;
            float dot = 0.f;
            int n = 0;
            if (ci < C) {
                n = candb[ci];
                const float* kr = keysA + (size_t)n * DIM;
                #pragma unroll
                for (int k = 0; k < 16; ++k) {
                    int o = sub * 4 + k * 32;
                    float4 kv = *(const float4*)(kr + o);
                    dot = fmaf(kv.x, qs[o+0], dot);
                    dot = fmaf(kv.y, qs[o+1], dot);
                    dot = fmaf(kv.z, qs[o+2], dot);
                    dot = fmaf(kv.w, qs[o+3], dot);
                }
            }
            dot += __shfl_xor(dot, 1);
            dot += __shfl_xor(dot, 2);
            dot += __shfl_xor(dot, 4);
            if (ci < C && sub == 0)
                dex[ci] = qnb + kn[a * NMEM + n] - 2.0f * dot;
        }
    }
    __syncthreads();

    // ---- exact (d, idx) rank -> top-50 in LDS ----
    for (int ci = tid; ci < C; ci += 1024) {
        float di = dex[ci]; int ni = candb[ci];
        int rank = 0;
        for (int j = 0; j < C; ++j) {
            float dj = dex[j];
            rank += (dj < di || (dj == di && candb[j] < ni)) ? 1 : 0;
        }
        if (rank < KNB) { wsel[rank] = 1.0f / (di + KDELTA); isel[rank] = ni; }
    }
    __syncthreads();
    if (tid == 0) {
        float ssum = 0.f;
        for (int i = 0; i < KNB; ++i) ssum += wsel[i];
        wsumS = ssum;
    }
    __syncthreads();
    if (tid < KNB) wsel[tid] = wsel[tid] / wsumS;
    __syncthreads();

    // ---- gather: 2 threads per dim, 25 k-terms each ----
    {
        int dim = tid & 511, h = tid >> 9;
        const float* va = vals + (size_t)a * NMEM * DIM + dim;
        float acc = 0.f;
        int k0 = h * 25;
        #pragma unroll 5
        for (int k = 0; k < 25; ++k)
            acc = fmaf(wsel[k0 + k], va[(size_t)isel[k0 + k] * DIM], acc);
        part[tid] = acc;
    }
    __syncthreads();
    if (tid < 512) {
        float e = part[tid] + part[tid + 512];
        emb_out[b * DIM + tid] = e;
        eb_out[b * DIM + tid] = bf16rn(e);
        qs[tid] = e;               // reuse qs as xs
        red[tid] = e * e;
    }
    __syncthreads();
    for (int s = 256; s > 0; s >>= 1) { if (tid < s) red[tid] += red[tid + s]; __syncthreads(); }
    if (tid == 0) {
        float q = red[0];
        qn_out[b] = q;
        if (step + 1 < NSTEPS) {
            int an = actions[b * NSTEPS + step + 1];
            float s = sqrtf(knv[an] + 4.f * q);
            Tb_out[b] = knm[an] - ZTHR * s;   // qn-less frame
            sw_out[b] = s;
        }
    }
    // ---- MLP layer 1: 256 outputs, 4-way split-K ----
    {
        int o = tid & (H1N - 1), q4 = tid >> 8;
        const float* wc = w1 + (size_t)q4 * 128 * H1N + o;
        const float* xc = qs + q4 * 128;
        float s = 0.f;
        #pragma unroll 8
        for (int d = 0; d < 128; ++d) s = fmaf(xc[d], wc[(size_t)d * H1N], s);
        part[tid] = s;
    }
    __syncthreads();
    if (tid < H1N) {
        float v = part[tid] + part[tid + H1N] + part[tid + 2 * H1N] + part[tid + 3 * H1N] + b1[tid];
        h1[tid] = v > 0.f ? v : expm1f(v);
    }
    __syncthreads();
    // ---- MLP layer 2: 128 outputs, 8-way split-K ----
    {
        int o = tid & (H2N - 1), q8 = tid >> 7;
        const float* wc = w2 + (size_t)q8 * 32 * H2N + o;
        const float* hc = h1 + q8 * 32;
        float s = 0.f;
        #pragma unroll 8
        for (int d = 0; d < 32; ++d) s = fmaf(hc[d], wc[(size_t)d * H2N], s);
        part[tid] = s;
    }
    __syncthreads();
    if (tid < H2N) {
        float v = b2[tid];
        #pragma unroll
        for (int q8 = 0; q8 < 8; ++q8) v += part[tid + q8 * H2N];
        h2[tid] = v > 0.f ? v : expm1f(v);
    }
    __syncthreads();
    if (tid < 5) {
        float p = b3[tid];
        for (int d = 0; d < H2N; ++d) p = fmaf(h2[d], w3[d * 5 + tid], p);
        float o = p;
        if (tid == 1) o = 1.0f / (1.0f + expf(-p));
        out[b * (6 * 5) + (step + 1) * 5 + tid] = o;
    }
}

extern "C" void kernel_launch(void* const* d_in, const int* in_sizes, int n_in,
                              void* d_out, int out_size, void* d_ws, size_t ws_size,
                              hipStream_t stream) {
    const float* x        = (const float*)d_in[0];
    const int*   actions  = (const int*)d_in[1];
    const float* mem_keys = (const float*)d_in[2];
    const float* mem_vals = (const float*)d_in[3];
    const float* w1 = (const float*)d_in[4];
    const float* b1 = (const float*)d_in[5];
    const float* w2 = (const float*)d_in[6];
    const float* b2 = (const float*)d_in[7];
    const float* w3 = (const float*)d_in[8];
    const float* b3 = (const float*)d_in[9];
    float* out = (float*)d_out;

    // workspace layout (bytes; 16B-aligned blocks)
    char* W = (char*)d_ws;
    unsigned short* kb    = (unsigned short*)W;                 // 76,800,000
    unsigned short* eb    = (unsigned short*)(W + 76800000);    //    262,144
    float* kn    = (float*)(W + 77062144);                      //    300,032
    float* qnb   = (float*)(W + 77362176);                      //      1,024
    float* emb   = (float*)(W + 77363200);                      //    524,288
    int*   perm  = (int*)(W + 77887488);                        //     15,360
    int*   cntb  = (int*)(W + 77902848);                        //        128
    float* knm   = (float*)(W + 77902976);                      //        128
    float* knv   = (float*)(W + 77903104);                      //        128
    float* Tb    = (float*)(W + 77903232);                      //      1,024
    float* sw    = (float*)(W + 77904256);                      //      1,024
    unsigned* ccnt_t       = (unsigned*)(W + 77905280);         //    400,384 (256*391*4)
    unsigned short* candt  = (unsigned short*)(W + 78305664);   //  2,402,304 (256*391*12*2)

    prep_keys_kernel<<<dim3((NACT * NMEM + 3) / 4), dim3(256), 0, stream>>>(mem_keys, kb, kn, NACT * NMEM);
    knstats_kernel<<<dim3(NACT), dim3(256), 0, stream>>>(kn, knm, knv);
    group_all_kernel<<<dim3(NSTEPS), dim3(256), 0, stream>>>(actions, perm, cntb);
    prep_predict_kernel<<<dim3(BATCH), dim3(256), 0, stream>>>(
        x, eb, qnb, actions, knm, knv, Tb, sw, w1, b1, w2, b2, w3, b3, out);

    const float* cur = x;
    for (int j = 0; j < NSTEPS; ++j) {
        dist_kernel<<<dim3(NACT, NYT), dim3(256), 0, stream>>>(
            eb, kb, kn, perm + j * NACT * BATCH, cntb + j * 4, Tb, ccnt_t, candt);
        selgp_kernel<<<dim3(BATCH), dim3(1024), 0, stream>>>(
            cur, eb, kb, mem_keys, kn, qnb, ccnt_t, candt, Tb, sw, actions, j, mem_vals,
            knm, knv, emb, eb, qnb, Tb, sw, w1, b1, w2, b2, w3, b3, out);
        cur = emb;
    }
}

// Round 21
// 445.887 us; speedup vs baseline: 1.0345x; 1.0345x over previous
//
#include <hip/hip_runtime.h>

#define BATCH 256
#define DIM 512
#define NACT 3
#define NMEM 25000
#define KNB 50
#define H1N 256
#define H2N 128
#define NSTEPS 5
#define KDELTA 0.001f

#define TB 128
#define TN 64
#define BK 64
#define NCH (DIM / BK)               // 8 k-chunks
#define NYT ((NMEM + TN - 1) / TN)   // 391 n-tiles

#define CAP 2048           // candidate buffer cap
#define MAXPT 12           // per-(row,tile) candidate slots; P(Poisson(0.52)>12) ~ 1e-15
#define ZTHR 2.40f         // expected ~205 candidates; P(cnt<128) ~ 3e-8 for Gaussian keys

typedef __attribute__((ext_vector_type(8))) short short8;
typedef __attribute__((ext_vector_type(4))) float f32x4;

__device__ __forceinline__ unsigned short bf16rn(float f) {
    unsigned u = __float_as_uint(f);
    u += 0x7FFFu + ((u >> 16) & 1u);
    return (unsigned short)(u >> 16);
}
__device__ __forceinline__ float blo(unsigned u) { return __uint_as_float(u << 16); }
__device__ __forceinline__ float bhi(unsigned u) { return __uint_as_float(u & 0xFFFF0000u); }

// ---------- prep keys: f32 -> bf16 copy + row norms (one wave per row) ----------
__global__ __launch_bounds__(256)
void prep_keys_kernel(const float* __restrict__ rows, unsigned short* __restrict__ kb,
                      float* __restrict__ kn, int nrows) {
    int wave = threadIdx.x >> 6, lane = threadIdx.x & 63;
    int r = blockIdx.x * 4 + wave;
    if (r >= nrows) return;
    const float* p = rows + (size_t)r * DIM;
    float4 v0 = *(const float4*)(p + lane * 8);
    float4 v1 = *(const float4*)(p + lane * 8 + 4);
    float f[8] = {v0.x, v0.y, v0.z, v0.w, v1.x, v1.y, v1.z, v1.w};
    short8 hv;
    float s = 0.f;
    #pragma unroll
    for (int i = 0; i < 8; ++i) { hv[i] = (short)bf16rn(f[i]); s += f[i] * f[i]; }
    *(short8*)(kb + (size_t)r * DIM + lane * 8) = hv;
    for (int off = 32; off; off >>= 1) s += __shfl_down(s, off);
    if (lane == 0) kn[r] = s;
}

// ---------- per-action kn stats (mean, var) ----------
__global__ __launch_bounds__(256)
void knstats_kernel(const float* __restrict__ kn, float* __restrict__ knm,
                    float* __restrict__ knv) {
    int a = blockIdx.x, tid = threadIdx.x;
    __shared__ float ss[256], qq[256];
    float s = 0.f, q = 0.f;
    for (int i = tid; i < NMEM; i += 256) {
        float v = kn[a * NMEM + i];
        s += v; q += v * v;
    }
    ss[tid] = s; qq[tid] = q;
    __syncthreads();
    for (int st = 128; st > 0; st >>= 1) {
        if (tid < st) { ss[tid] += ss[tid + st]; qq[tid] += qq[tid + st]; }
        __syncthreads();
    }
    if (tid == 0) {
        float mean = ss[0] / (float)NMEM;
        knm[a] = mean;
        knv[a] = fmaxf(qq[0] / (float)NMEM - mean * mean, 0.f);
    }
}

// ---------- group batch rows by action, all steps in one launch ----------
__global__ __launch_bounds__(256)
void group_all_kernel(const int* __restrict__ actions,
                      int* __restrict__ perm, int* __restrict__ cnt) {
    int step = blockIdx.x;
    __shared__ int lcnt[NACT];
    __shared__ int lperm[NACT * BATCH];
    int tid = threadIdx.x;
    if (tid < NACT) lcnt[tid] = 0;
    __syncthreads();
    int a = actions[tid * NSTEPS + step];
    int pos = atomicAdd(&lcnt[a], 1);
    lperm[a * BATCH + pos] = tid;
    __syncthreads();
    if (tid < NACT) cnt[step * 4 + tid] = lcnt[tid];
    for (int aa = 0; aa < NACT; ++aa) {
        int c = lcnt[aa];
        int f = (c > 0) ? lperm[aa * BATCH] : 0;
        for (int i = c + tid; i < BATCH; i += 256) lperm[aa * BATCH + i] = f;
    }
    __syncthreads();
    for (int i = tid; i < NACT * BATCH; i += 256)
        perm[step * NACT * BATCH + i] = lperm[i];
}

// ---------- step-0: prep x (bf16 + qn + analytic threshold) fused with first MLP ----------
// Tb is in the qn-LESS frame: d' = kn - 2 q.k  <  knm - z*s   (qn cancels)
__global__ __launch_bounds__(256)
void prep_predict_kernel(const float* __restrict__ x, unsigned short* __restrict__ eb,
                         float* __restrict__ qn, const int* __restrict__ actions,
                         const float* __restrict__ knm, const float* __restrict__ knv,
                         float* __restrict__ Tb, float* __restrict__ sw,
                         const float* __restrict__ w1, const float* __restrict__ b1,
                         const float* __restrict__ w2, const float* __restrict__ b2,
                         const float* __restrict__ w3, const float* __restrict__ b3,
                         float* __restrict__ out) {
    int b = blockIdx.x, tid = threadIdx.x;
    __shared__ float xs[DIM];
    __shared__ float red[256];
    __shared__ float h1[H1N];
    __shared__ float h2[H2N];
    float e0 = x[(size_t)b * DIM + tid];
    float e1 = x[(size_t)b * DIM + tid + 256];
    xs[tid] = e0; xs[tid + 256] = e1;
    eb[(size_t)b * DIM + tid] = bf16rn(e0);
    eb[(size_t)b * DIM + tid + 256] = bf16rn(e1);
    red[tid] = e0 * e0 + e1 * e1;
    __syncthreads();
    for (int s = 128; s > 0; s >>= 1) { if (tid < s) red[tid] += red[tid + s]; __syncthreads(); }
    if (tid == 0) {
        float q = red[0];
        qn[b] = q;
        int a0 = actions[b * NSTEPS];
        float s = sqrtf(knv[a0] + 4.f * q);
        Tb[b] = knm[a0] - ZTHR * s;     // qn-less frame
        sw[b] = s;
    }
    float acc = b1[tid];
    #pragma unroll 8
    for (int d = 0; d < DIM; ++d) acc = fmaf(xs[d], w1[d * H1N + tid], acc);
    h1[tid] = acc > 0.f ? acc : expm1f(acc);
    __syncthreads();
    if (tid < H2N) {
        float a2 = b2[tid];
        #pragma unroll 8
        for (int d = 0; d < H1N; ++d) a2 = fmaf(h1[d], w2[d * H2N + tid], a2);
        h2[tid] = a2 > 0.f ? a2 : expm1f(a2);
    }
    __syncthreads();
    if (tid < 5) {
        float p = b3[tid];
        for (int d = 0; d < H2N; ++d) p = fmaf(h2[d], w3[d * 5 + tid], p);
        float o = p;
        if (tid == 1) o = 1.0f / (1.0f + expf(-p));
        out[b * (6 * 5) + tid] = o;
    }
}

// ---------- approx distance GEMM + owner-computes LDS candidate collect ----------
// block (a, yt) exclusively owns cells (b in rows, n in tile yt): no global atomics.
__global__ __launch_bounds__(256)
void dist_kernel(const unsigned short* __restrict__ eb, const unsigned short* __restrict__ kb,
                 const float* __restrict__ kn, const int* __restrict__ perm,
                 const int* __restrict__ cnt, const float* __restrict__ Tb,
                 unsigned* __restrict__ ccnt_t, unsigned short* __restrict__ candt) {
    int a = blockIdx.x;
    int c = cnt[a];
    int yt = blockIdx.y;
    int n0 = yt * TN;

    __shared__ __align__(16) unsigned short Qh[2][TB][BK];
    __shared__ __align__(16) unsigned short Kh[2][TN][BK];
    __shared__ int rows[TB];
    __shared__ float Tl[TB];
    __shared__ unsigned pcnt[TB];
    __shared__ unsigned short pids[TB][MAXPT];

    int tid = threadIdx.x;
    int lane = tid & 63, wave = tid >> 6;
    int wm = wave >> 1, wn = wave & 1;

    const int qr = tid >> 1, qc = (tid & 1) * 32, qswz = (qr & 7) * 8;
    const int kr = tid >> 2, kc = (tid & 3) * 16, kswz = (kr & 7) * 8;
    int krow = (n0 + kr < NMEM) ? (n0 + kr) : (NMEM - 1);
    const unsigned short* ksrc = kb + ((size_t)a * NMEM + krow) * DIM + kc;

    int nn[2]; float knv2[2]; bool nvalid[2];
    #pragma unroll
    for (int nf = 0; nf < 2; ++nf) {
        nn[nf] = n0 + wn * 32 + nf * 16 + (lane & 15);
        nvalid[nf] = nn[nf] < NMEM;
        knv2[nf] = nvalid[nf] ? kn[a * NMEM + nn[nf]] : 0.f;
    }

    for (int tb0 = 0; tb0 < c; tb0 += TB) {
        __syncthreads();
        if (tid < TB) {
            int i = tb0 + tid;
            int rr = perm[a * BATCH + (i < c ? i : 0)];
            rows[tid] = rr;
            Tl[tid] = Tb[rr];
            pcnt[tid] = 0;
        }
        __syncthreads();

        const int mlim = c - tb0;   // rows >= mlim are duplicates of row 0
        const unsigned short* qsrc = eb + (size_t)rows[qr] * DIM + qc;
        f32x4 acc[4][2] = {};
        short8 qA[4], qB[4], kA[2], kB[2];

        #pragma unroll
        for (int j = 0; j < 4; ++j) qA[j] = *(const short8*)(qsrc + j * 8);
        kA[0] = *(const short8*)(ksrc);
        kA[1] = *(const short8*)(ksrc + 8);
        #pragma unroll
        for (int j = 0; j < 4; ++j) qB[j] = *(const short8*)(qsrc + BK + j * 8);
        kB[0] = *(const short8*)(ksrc + BK);
        kB[1] = *(const short8*)(ksrc + BK + 8);
        #pragma unroll
        for (int j = 0; j < 4; ++j) *(short8*)&Qh[0][qr][(qc + j * 8) ^ qswz] = qA[j];
        *(short8*)&Kh[0][kr][(kc + 0) ^ kswz] = kA[0];
        *(short8*)&Kh[0][kr][(kc + 8) ^ kswz] = kA[1];
        __syncthreads();

        auto mfma_phase = [&](int B) {
            #pragma unroll
            for (int kk = 0; kk < BK; kk += 32) {
                int kcol = kk + (lane >> 4) * 8;
                short8 av[4], bv[2];
                #pragma unroll
                for (int nf = 0; nf < 2; ++nf) {
                    int n = wn * 32 + nf * 16 + (lane & 15);
                    bv[nf] = *(const short8*)&Kh[B][n][kcol ^ ((n & 7) * 8)];
                }
                #pragma unroll
                for (int mf = 0; mf < 4; ++mf) {
                    if (wm * 64 + mf * 16 < mlim) {
                        int m = wm * 64 + mf * 16 + (lane & 15);
                        av[mf] = *(const short8*)&Qh[B][m][kcol ^ ((m & 7) * 8)];
                        #pragma unroll
                        for (int nf = 0; nf < 2; ++nf)
                            acc[mf][nf] = __builtin_amdgcn_mfma_f32_16x16x32_bf16(av[mf], bv[nf], acc[mf][nf], 0, 0, 0);
                    }
                }
            }
        };

        #pragma unroll
        for (int p = 0; p < NCH / 2; ++p) {
            const int it = 2 * p;
            if (it + 2 < NCH) {
                const int d0 = (it + 2) * BK;
                #pragma unroll
                for (int j = 0; j < 4; ++j) qA[j] = *(const short8*)(qsrc + d0 + j * 8);
                kA[0] = *(const short8*)(ksrc + d0);
                kA[1] = *(const short8*)(ksrc + d0 + 8);
            }
            mfma_phase(0);
            {
                #pragma unroll
                for (int j = 0; j < 4; ++j) *(short8*)&Qh[1][qr][(qc + j * 8) ^ qswz] = qB[j];
                *(short8*)&Kh[1][kr][(kc + 0) ^ kswz] = kB[0];
                *(short8*)&Kh[1][kr][(kc + 8) ^ kswz] = kB[1];
                __syncthreads();
            }
            if (it + 3 < NCH) {
                const int d0 = (it + 3) * BK;
                #pragma unroll
                for (int j = 0; j < 4; ++j) qB[j] = *(const short8*)(qsrc + d0 + j * 8);
                kB[0] = *(const short8*)(ksrc + d0);
                kB[1] = *(const short8*)(ksrc + d0 + 8);
            }
            mfma_phase(1);
            if (it + 2 < NCH) {
                #pragma unroll
                for (int j = 0; j < 4; ++j) *(short8*)&Qh[0][qr][(qc + j * 8) ^ qswz] = qA[j];
                *(short8*)&Kh[0][kr][(kc + 0) ^ kswz] = kA[0];
                *(short8*)&Kh[0][kr][(kc + 8) ^ kswz] = kA[1];
                __syncthreads();
            }
        }

        // ---- epilogue: threshold compare -> LDS collect (no dist-buffer store) ----
        #pragma unroll
        for (int mf = 0; mf < 4; ++mf) {
            if (wm * 64 + mf * 16 >= mlim) continue;
            #pragma unroll
            for (int r = 0; r < 4; ++r) {
                int m = wm * 64 + mf * 16 + (lane >> 4) * 4 + r;
                if (m >= mlim) continue;          // dup rows: never collect
                float Tv = Tl[m];
                #pragma unroll
                for (int nf = 0; nf < 2; ++nf) {
                    if (nvalid[nf]) {
                        float d = knv2[nf] - 2.0f * acc[mf][nf][r];
                        if (d < Tv) {
                            unsigned p = atomicAdd(&pcnt[m], 1u);
                            if (p < MAXPT) pids[m][p] = (unsigned short)nn[nf];
                        }
                    }
                }
            }
        }
        __syncthreads();
        // flush: plain stores, exclusive (b, yt) ownership
        if (tid < mlim) {
            int b = rows[tid];
            unsigned c0 = pcnt[tid];
            size_t slot = (size_t)b * NYT + yt;
            ccnt_t[slot] = c0;
            int w = c0 < MAXPT ? (int)c0 : MAXPT;
            for (int i = 0; i < w; ++i)
                candt[slot * MAXPT + i] = pids[tid][i];
        }
    }
}

// ---------- fused: assemble candidates -> exact refine -> top-50 -> gather -> MLP ----------
__global__ __launch_bounds__(1024)
void selgp_kernel(const float* __restrict__ emb, const unsigned short* __restrict__ eb,
                  const unsigned short* __restrict__ kb,
                  const float* __restrict__ keys, const float* __restrict__ kn,
                  const float* __restrict__ qn,
                  const unsigned* __restrict__ ccnt_t, const unsigned short* __restrict__ candt,
                  const float* __restrict__ Tb_in, const float* __restrict__ sw_in,
                  const int* __restrict__ actions, int step,
                  const float* __restrict__ vals,
                  const float* __restrict__ knm, const float* __restrict__ knv,
                  float* __restrict__ emb_out, unsigned short* __restrict__ eb_out,
                  float* __restrict__ qn_out, float* __restrict__ Tb_out,
                  float* __restrict__ sw_out,
                  const float* __restrict__ w1, const float* __restrict__ b1,
                  const float* __restrict__ w2, const float* __restrict__ b2,
                  const float* __restrict__ w3, const float* __restrict__ b3,
                  float* __restrict__ out) {
    __shared__ float qs[DIM];          // q row (refine), later reused as new-emb xs
    __shared__ int tcnt[512];
    __shared__ int ovfS;
    __shared__ unsigned cntS;
    __shared__ int candb[CAP];
    __shared__ float dex[CAP];
    __shared__ float wsel[KNB];
    __shared__ int   isel[KNB];
    __shared__ float wsumS;
    __shared__ float part[1024];
    __shared__ float red[512];
    __shared__ float h1[H1N];
    __shared__ float h2[H2N];

    int b = blockIdx.x, tid = threadIdx.x;
    int a = actions[b * NSTEPS + step];

    if (tid < 128) *(float4*)&qs[tid * 4] = *(const float4*)(emb + (size_t)b * DIM + tid * 4);

    // ---- assemble candidate list from per-tile slots ----
    int own = 0;
    if (tid < 512) tcnt[tid] = 0;
    if (tid == 0) ovfS = 0;
    __syncthreads();
    if (tid < NYT) {
        unsigned c0 = ccnt_t[(size_t)b * NYT + tid];
        own = (c0 > MAXPT) ? MAXPT : (int)c0;
        tcnt[tid] = own;
        if (c0 > MAXPT) ovfS = 1;     // benign race: any writer sets 1
    }
    __syncthreads();
    for (int off2 = 1; off2 < 512; off2 <<= 1) {
        int add = (tid < 512 && tid >= off2) ? tcnt[tid - off2] : 0;
        __syncthreads();
        if (tid < 512) tcnt[tid] += add;
        __syncthreads();
    }
    int C = tcnt[511];
    bool fb = (ovfS != 0) || (C < 128) || (C > CAP);
    if (!fb) {
        if (tid < NYT && own > 0) {
            int o = tcnt[tid] - own;
            size_t slot = (size_t)b * NYT + tid;
            for (int i = 0; i < own; ++i)
                candb[o + i] = (int)candt[slot * MAXPT + i];
        }
        __syncthreads();
    } else {
        // ---- fallback: brute-force recompute (bf16 inputs, f32 accum) + widen/tighten ----
        float T = Tb_in[b], sd = sw_in[b];
        for (int it = 0; it < 10; ++it) {
            if (tid == 0) cntS = 0;
            __syncthreads();
            for (int n = tid; n < NMEM; n += 1024) {
                const unsigned short* kr = kb + ((size_t)a * NMEM + n) * DIM;
                float dot = 0.f;
                for (int dd = 0; dd < DIM; dd += 2) {
                    unsigned u = *(const unsigned*)(kr + dd);
                    dot = fmaf(blo(u), qs[dd], dot);
                    dot = fmaf(bhi(u), qs[dd + 1], dot);
                }
                float d = kn[a * NMEM + n] - 2.0f * dot;
                if (d < T) { unsigned p = atomicAdd(&cntS, 1u); if (p < CAP) candb[p] = n; }
            }
            __syncthreads();
            if (cntS >= 128 && cntS <= CAP) break;
            T += (cntS > CAP) ? -0.3f * sd : 0.6f * sd;
            __syncthreads();
        }
        C = (int)cntS; if (C > CAP) C = CAP;
    }

    // ---- exact f32 refine (8 threads/cand, interleaved dims: conflict-free) ----
    float qnb = qn[b];
    const float* keysA = keys + (size_t)a * NMEM * DIM;
    {
        int cslot = tid >> 3, sub = tid & 7;
        int sweeps = (C + 127) >> 7;
        for (int sw = 0; sw < sweeps; ++sw) {
            int ci = sw * 128 + cslot;
            float dot = 0.f;
            int n = 0;
            if (ci < C) {
                n = candb[ci];
                const float* kr = keysA + (size_t)n * DIM;
                #pragma unroll
                for (int k = 0; k < 16; ++k) {
                    int o = sub * 4 + k * 32;
                    float4 kv = *(const float4*)(kr + o);
                    dot = fmaf(kv.x, qs[o+0], dot);
                    dot = fmaf(kv.y, qs[o+1], dot);
                    dot = fmaf(kv.z, qs[o+2], dot);
                    dot = fmaf(kv.w, qs[o+3], dot);
                }
            }
            dot += __shfl_xor(dot, 1);
            dot += __shfl_xor(dot, 2);
            dot += __shfl_xor(dot, 4);
            if (ci < C && sub == 0)
                dex[ci] = qnb + kn[a * NMEM + n] - 2.0f * dot;
        }
    }
    __syncthreads();

    // ---- exact (d, idx) rank -> top-50 in LDS ----
    for (int ci = tid; ci < C; ci += 1024) {
        float di = dex[ci]; int ni = candb[ci];
        int rank = 0;
        for (int j = 0; j < C; ++j) {
            float dj = dex[j];
            rank += (dj < di || (dj == di && candb[j] < ni)) ? 1 : 0;
        }
        if (rank < KNB) { wsel[rank] = 1.0f / (di + KDELTA); isel[rank] = ni; }
    }
    __syncthreads();
    if (tid == 0) {
        float ssum = 0.f;
        for (int i = 0; i < KNB; ++i) ssum += wsel[i];
        wsumS = ssum;
    }
    __syncthreads();
    if (tid < KNB) wsel[tid] = wsel[tid] / wsumS;
    __syncthreads();

    // ---- gather: 2 threads per dim, 25 k-terms each ----
    {
        int dim = tid & 511, h = tid >> 9;
        const float* va = vals + (size_t)a * NMEM * DIM + dim;
        float acc = 0.f;
        int k0 = h * 25;
        #pragma unroll 5
        for (int k = 0; k < 25; ++k)
            acc = fmaf(wsel[k0 + k], va[(size_t)isel[k0 + k] * DIM], acc);
        part[tid] = acc;
    }
    __syncthreads();
    if (tid < 512) {
        float e = part[tid] + part[tid + 512];
        emb_out[b * DIM + tid] = e;
        eb_out[b * DIM + tid] = bf16rn(e);
        qs[tid] = e;               // reuse qs as xs
        red[tid] = e * e;
    }
    __syncthreads();
    for (int s = 256; s > 0; s >>= 1) { if (tid < s) red[tid] += red[tid + s]; __syncthreads(); }
    if (tid == 0) {
        float q = red[0];
        qn_out[b] = q;
        if (step + 1 < NSTEPS) {
            int an = actions[b * NSTEPS + step + 1];
            float s = sqrtf(knv[an] + 4.f * q);
            Tb_out[b] = knm[an] - ZTHR * s;   // qn-less frame
            sw_out[b] = s;
        }
    }
    // ---- MLP layer 1: 256 outputs, 4-way split-K ----
    {
        int o = tid & (H1N - 1), q4 = tid >> 8;
        const float* wc = w1 + (size_t)q4 * 128 * H1N + o;
        const float* xc = qs + q4 * 128;
        float s = 0.f;
        #pragma unroll 8
        for (int d = 0; d < 128; ++d) s = fmaf(xc[d], wc[(size_t)d * H1N], s);
        part[tid] = s;
    }
    __syncthreads();
    if (tid < H1N) {
        float v = part[tid] + part[tid + H1N] + part[tid + 2 * H1N] + part[tid + 3 * H1N] + b1[tid];
        h1[tid] = v > 0.f ? v : expm1f(v);
    }
    __syncthreads();
    // ---- MLP layer 2: 128 outputs, 8-way split-K ----
    {
        int o = tid & (H2N - 1), q8 = tid >> 7;
        const float* wc = w2 + (size_t)q8 * 32 * H2N + o;
        const float* hc = h1 + q8 * 32;
        float s = 0.f;
        #pragma unroll 8
        for (int d = 0; d < 32; ++d) s = fmaf(hc[d], wc[(size_t)d * H2N], s);
        part[tid] = s;
    }
    __syncthreads();
    if (tid < H2N) {
        float v = b2[tid];
        #pragma unroll
        for (int q8 = 0; q8 < 8; ++q8) v += part[tid + q8 * H2N];
        h2[tid] = v > 0.f ? v : expm1f(v);
    }
    __syncthreads();
    if (tid < 5) {
        float p = b3[tid];
        for (int d = 0; d < H2N; ++d) p = fmaf(h2[d], w3[d * 5 + tid], p);
        float o = p;
        if (tid == 1) o = 1.0f / (1.0f + expf(-p));
        out[b * (6 * 5) + (step + 1) * 5 + tid] = o;
    }
}

extern "C" void kernel_launch(void* const* d_in, const int* in_sizes, int n_in,
                              void* d_out, int out_size, void* d_ws, size_t ws_size,
                              hipStream_t stream) {
    const float* x        = (const float*)d_in[0];
    const int*   actions  = (const int*)d_in[1];
    const float* mem_keys = (const float*)d_in[2];
    const float* mem_vals = (const float*)d_in[3];
    const float* w1 = (const float*)d_in[4];
    const float* b1 = (const float*)d_in[5];
    const float* w2 = (const float*)d_in[6];
    const float* b2 = (const float*)d_in[7];
    const float* w3 = (const float*)d_in[8];
    const float* b3 = (const float*)d_in[9];
    float* out = (float*)d_out;

    // workspace layout (bytes; 16B-aligned blocks)
    char* W = (char*)d_ws;
    unsigned short* kb    = (unsigned short*)W;                 // 76,800,000
    unsigned short* eb    = (unsigned short*)(W + 76800000);    //    262,144
    float* kn    = (float*)(W + 77062144);                      //    300,032
    float* qnb   = (float*)(W + 77362176);                      //      1,024
    float* emb   = (float*)(W + 77363200);                      //    524,288
    int*   perm  = (int*)(W + 77887488);                        //     15,360
    int*   cntb  = (int*)(W + 77902848);                        //        128
    float* knm   = (float*)(W + 77902976);                      //        128
    float* knv   = (float*)(W + 77903104);                      //        128
    float* Tb    = (float*)(W + 77903232);                      //      1,024
    float* sw    = (float*)(W + 77904256);                      //      1,024
    unsigned* ccnt_t       = (unsigned*)(W + 77905280);         //    400,384 (256*391*4)
    unsigned short* candt  = (unsigned short*)(W + 78305664);   //  2,402,304 (256*391*12*2)

    prep_keys_kernel<<<dim3((NACT * NMEM + 3) / 4), dim3(256), 0, stream>>>(mem_keys, kb, kn, NACT * NMEM);
    knstats_kernel<<<dim3(NACT), dim3(256), 0, stream>>>(kn, knm, knv);
    group_all_kernel<<<dim3(NSTEPS), dim3(256), 0, stream>>>(actions, perm, cntb);
    prep_predict_kernel<<<dim3(BATCH), dim3(256), 0, stream>>>(
        x, eb, qnb, actions, knm, knv, Tb, sw, w1, b1, w2, b2, w3, b3, out);

    const float* cur = x;
    for (int j = 0; j < NSTEPS; ++j) {
        dist_kernel<<<dim3(NACT, NYT), dim3(256), 0, stream>>>(
            eb, kb, kn, perm + j * NACT * BATCH, cntb + j * 4, Tb, ccnt_t, candt);
        selgp_kernel<<<dim3(BATCH), dim3(1024), 0, stream>>>(
            cur, eb, kb, mem_keys, kn, qnb, ccnt_t, candt, Tb, sw, actions, j, mem_vals,
            knm, knv, emb, eb, qnb, Tb, sw, w1, b1, w2, b2, w3, b3, out);
        cur = emb;
    }
}